// Round 7
// baseline (199.431 us; speedup 1.0000x reference)
//
#include <hip/hip_runtime.h>
#include <math.h>

#define KB_NUM 512
#define DIMC 64
#define BSZ 32
#define TLEN 4096
#define NTOK (BSZ * TLEN)          // 131072
#define DECAY_F 0.99f
#define EPS_F 1e-5f
#define K2_SPAN 512                // tokens per block (bin kernel)
#define MTOK 128                   // tokens per block (main kernel)

// output offsets (flat f32, reference return order)
#define Q_OFF    ((size_t)0)
#define IDX_OFF  ((size_t)BSZ * DIMC * TLEN)        // 8388608
#define LOSS_OFF (IDX_OFF + (size_t)NTOK)           // 8519680
#define PLEX_OFF (LOSS_OFF + 1)                     // 8519681
#define NEMB_OFF (PLEX_OFF + 1)                     // 8519682
#define NCS_OFF  (NEMB_OFF + (size_t)KB_NUM * DIMC) // 8552450
#define NEA_OFF  (NCS_OFF + (size_t)KB_NUM)         // 8552962

typedef _Float16 f16x8 __attribute__((ext_vector_type(8)));
typedef float    f32x4 __attribute__((ext_vector_type(4)));

// ---------------------------------------------------------------------------
// Kernel 0: prep embedding — f16 hi/lo split + 0.5*||e||^2 (fp32)
// ---------------------------------------------------------------------------
__global__ __launch_bounds__(64) void vq_prep_e(
    const float* __restrict__ emb,
    _Float16* __restrict__ eh,
    _Float16* __restrict__ el,
    float* __restrict__ enorm)
{
    const int k = blockIdx.x;
    const int c = threadIdx.x;
    float v = emb[(size_t)k * DIMC + c];
    _Float16 h = (_Float16)v;
    eh[(size_t)k * DIMC + c] = h;
    el[(size_t)k * DIMC + c] = (_Float16)(v - (float)h);
    float s = v * v;
    #pragma unroll
    for (int off = 32; off > 0; off >>= 1)
        s += __shfl_down(s, off, 64);
    if (c == 0) enorm[k] = 0.5f * s;
}

// ---------------------------------------------------------------------------
// Kernel 1: MFMA argmin + quantize + loss
// block = 256 thr = 4 waves; tile = 128 tokens x 512 codes (full K).
// Wave w owns tokens [w*32, w*32+32): 2 token-tiles x 32 code-tiles,
// K=64 in 2 MFMA k-steps. 4-term f16 hi/lo MFMA = fp32-class precision.
// LDS 33.3 KB -> 4 blocks/CU -> 4 waves/SIMD (vs 2 last round).
// Fragment maps identical to round-6 (verified passing).
// ---------------------------------------------------------------------------
__global__ __launch_bounds__(256, 4) void vq_main_kernel(
    const float* __restrict__ z,
    const float* __restrict__ emb,
    const _Float16* __restrict__ eh,
    const _Float16* __restrict__ el,
    const float* __restrict__ enorm,
    float* __restrict__ out,
    float* __restrict__ lossAcc)
{
    __shared__ float zs[MTOK * 65];   // [token][ch], pad 65 -> conflict-free

    const int tid = threadIdx.x;
    const int w   = tid >> 6;
    const int ln  = tid & 63;
    const int bk  = blockIdx.x;
    const int b   = bk >> 5;               // 32 blocks per batch row
    const int t0  = (bk & 31) << 7;        // 128 tokens per block

    const float* zg = z + (size_t)b * (DIMC * TLEN) + t0;

    // stage: transpose z[c][t] -> zs[t][c]; 2 threads per token (ch halves).
    // Global: fixed c, lanes -> consecutive tokens (coalesced dwords).
    // LDS bank = (tok + c) % 32 -> conflict-free.
    {
        const int tok   = tid & (MTOK - 1);
        const int chalf = (tid >> 7) * 32;
        #pragma unroll 8
        for (int j = 0; j < 32; ++j)
            zs[tok * 65 + chalf + j] = zg[(size_t)(chalf + j) * TLEN + tok];
    }
    __syncthreads();

    // build B fragments once (held in VGPRs for the whole K-loop)
    f16x8 zhf[2][2], zlf[2][2];
    #pragma unroll
    for (int tt = 0; tt < 2; ++tt) {
        #pragma unroll
        for (int ks = 0; ks < 2; ++ks) {
            const float* zrow = &zs[(w * 32 + tt * 16 + (ln & 15)) * 65
                                    + ks * 32 + ((ln >> 4) << 3)];
            #pragma unroll
            for (int j = 0; j < 8; ++j) {
                float v = zrow[j];
                _Float16 h = (_Float16)v;
                zhf[tt][ks][j] = h;
                zlf[tt][ks][j] = (_Float16)(v - (float)h);
            }
        }
    }

    float bv[2] = {3.4e38f, 3.4e38f};
    int   bi[2] = {0, 0};

    #pragma unroll 1
    for (int chunk = 0; chunk < 8; ++chunk) {        // 64 codes per chunk
        f32x4 acc[4][2];
        #pragma unroll
        for (int ct = 0; ct < 4; ++ct)
            #pragma unroll
            for (int tt = 0; tt < 2; ++tt)
                acc[ct][tt] = (f32x4){0.f, 0.f, 0.f, 0.f};

        #pragma unroll
        for (int ct = 0; ct < 4; ++ct) {
            const int crow = chunk * 64 + ct * 16 + (ln & 15);
            f16x8 ah[2], al[2];
            #pragma unroll
            for (int ks = 0; ks < 2; ++ks) {
                const size_t aoff = (size_t)crow * DIMC + ks * 32 + ((ln >> 4) << 3);
                ah[ks] = *(const f16x8*)(eh + aoff);
                al[ks] = *(const f16x8*)(el + aoff);
            }
            #pragma unroll
            for (int ks = 0; ks < 2; ++ks) {
                #pragma unroll
                for (int tt = 0; tt < 2; ++tt)
                    acc[ct][tt] = __builtin_amdgcn_mfma_f32_16x16x32_f16(
                        ah[ks], zhf[tt][ks], acc[ct][tt], 0, 0, 0);
                #pragma unroll
                for (int tt = 0; tt < 2; ++tt)
                    acc[ct][tt] = __builtin_amdgcn_mfma_f32_16x16x32_f16(
                        ah[ks], zlf[tt][ks], acc[ct][tt], 0, 0, 0);
                #pragma unroll
                for (int tt = 0; tt < 2; ++tt)
                    acc[ct][tt] = __builtin_amdgcn_mfma_f32_16x16x32_f16(
                        al[ks], zhf[tt][ks], acc[ct][tt], 0, 0, 0);
                #pragma unroll
                for (int tt = 0; tt < 2; ++tt)
                    acc[ct][tt] = __builtin_amdgcn_mfma_f32_16x16x32_f16(
                        al[ks], zlf[tt][ks], acc[ct][tt], 0, 0, 0);
            }
        }

        // fold: s = 0.5||e||^2 - z.e ; ascending code order (chunk, ct, reg)
        #pragma unroll
        for (int ct = 0; ct < 4; ++ct) {
            const int cb = chunk * 64 + ct * 16 + ((ln >> 4) << 2);
            float4 en = *(const float4*)(enorm + cb);
            const float e0 = en.x, e1 = en.y, e2 = en.z, e3 = en.w;
            #pragma unroll
            for (int tt = 0; tt < 2; ++tt) {
                float s0 = e0 - acc[ct][tt][0];
                float s1 = e1 - acc[ct][tt][1];
                float s2 = e2 - acc[ct][tt][2];
                float s3 = e3 - acc[ct][tt][3];
                if (s0 < bv[tt]) { bv[tt] = s0; bi[tt] = cb; }
                if (s1 < bv[tt]) { bv[tt] = s1; bi[tt] = cb + 1; }
                if (s2 < bv[tt]) { bv[tt] = s2; bi[tt] = cb + 2; }
                if (s3 < bv[tt]) { bv[tt] = s3; bi[tt] = cb + 3; }
            }
        }
    }

    // cross-lane fold over the 4 row-groups (lane>>4); lower index wins ties
    #pragma unroll
    for (int mask = 16; mask <= 32; mask <<= 1) {
        #pragma unroll
        for (int tt = 0; tt < 2; ++tt) {
            float ov = __shfl_xor(bv[tt], mask, 64);
            int   oi = __shfl_xor(bi[tt], mask, 64);
            if (ov < bv[tt] || (ov == bv[tt] && oi < bi[tt])) {
                bv[tt] = ov; bi[tt] = oi;
            }
        }
    }

    // epilogue: lane -> token T = w*32 + (ln>>5)*16 + (ln&15),
    //           channel half chalf = ((ln>>4)&1)*32. Two lanes per token.
    const int tte   = ln >> 5;
    const int idxv  = tte ? bi[1] : bi[0];
    const int tok   = w * 32 + tte * 16 + (ln & 15);
    const int chalf = ((ln >> 4) & 1) * 32;

    if (((ln >> 4) & 1) == 0)
        out[IDX_OFF + (size_t)b * TLEN + t0 + tok] = (float)idxv;

    const float* er   = emb + (size_t)idxv * DIMC + chalf;  // fp32 codebook row
    const float* zrow = &zs[tok * 65 + chalf];
    float* qo = out + (size_t)b * (DIMC * TLEN) + t0 + tok + (size_t)chalf * TLEN;

    float lsum = 0.f;
    #pragma unroll
    for (int c4 = 0; c4 < 8; ++c4) {
        float4 ev = *(const float4*)(er + c4 * 4);
        float z0 = zrow[c4 * 4 + 0], z1 = zrow[c4 * 4 + 1];
        float z2 = zrow[c4 * 4 + 2], z3 = zrow[c4 * 4 + 3];
        float d0 = ev.x - z0, d1 = ev.y - z1, d2 = ev.z - z2, d3 = ev.w - z3;
        qo[(size_t)(c4 * 4 + 0) * TLEN] = z0 + d0;   // z + (q - z), ref rounding
        qo[(size_t)(c4 * 4 + 1) * TLEN] = z1 + d1;
        qo[(size_t)(c4 * 4 + 2) * TLEN] = z2 + d2;
        qo[(size_t)(c4 * 4 + 3) * TLEN] = z3 + d3;
        lsum = fmaf(d0, d0, lsum); lsum = fmaf(d1, d1, lsum);
        lsum = fmaf(d2, d2, lsum); lsum = fmaf(d3, d3, lsum);
    }

    #pragma unroll
    for (int off = 32; off > 0; off >>= 1)
        lsum += __shfl_down(lsum, off, 64);
    if (ln == 0) atomicAdd(lossAcc, lsum);
}

// ---------------------------------------------------------------------------
// Kernel 2: segment-sum binning via LDS accumulator, replica-atomic flush
// grid = NTOK/K2_SPAN = 256 blocks x 256 thr; 1 block/CU (135 KB LDS)
// ---------------------------------------------------------------------------
__global__ __launch_bounds__(256, 1) void vq_bin_kernel(
    const float* __restrict__ z,
    const float* __restrict__ out,    // reads idx at IDX_OFF
    float* __restrict__ cnt,          // [R][KB_NUM]
    float* __restrict__ esum,         // [R][KB_NUM*DIMC]
    int R)
{
    __shared__ float acc[KB_NUM][DIMC + 1];
    __shared__ float scnt[KB_NUM];

    const int tid = threadIdx.x;
    for (int j = tid; j < KB_NUM * (DIMC + 1); j += 256) ((float*)acc)[j] = 0.f;
    for (int j = tid; j < KB_NUM; j += 256) scnt[j] = 0.f;
    __syncthreads();

    const int gt0 = blockIdx.x * K2_SPAN;
    #pragma unroll
    for (int it = 0; it < K2_SPAN / 256; ++it) {
        const int gt = gt0 + it * 256 + tid;
        const int b  = gt >> 12;
        const int t  = gt & (TLEN - 1);
        const int idx = (int)out[IDX_OFF + gt];
        atomicAdd(&scnt[idx], 1.0f);
        const float* zp = z + (size_t)b * (DIMC * TLEN) + t;
        #pragma unroll 4
        for (int c = 0; c < DIMC; ++c) {
            float zv = zp[(size_t)c * TLEN];
            atomicAdd(&acc[idx][c], zv);
        }
    }
    __syncthreads();

    const int r = (int)((unsigned)blockIdx.x % (unsigned)R);
    for (int j = tid; j < KB_NUM * DIMC; j += 256) {
        const int k = j >> 6, c = j & 63;
        float v = acc[k][c];
        if (v != 0.f) atomicAdd(esum + (size_t)r * (KB_NUM * DIMC) + j, v);
    }
    for (int j = tid; j < KB_NUM; j += 256) {
        float v = scnt[j];
        if (v != 0.f) atomicAdd(cnt + (size_t)r * KB_NUM + j, v);
    }
}

// ---------------------------------------------------------------------------
// Kernel 3: stats — new_cluster_size, n_tot, perplexity, loss
// ---------------------------------------------------------------------------
__global__ __launch_bounds__(512) void vq_stats_kernel(
    const float* __restrict__ cluster_size,
    const float* __restrict__ cnt,
    const float* __restrict__ lossAcc,
    float* __restrict__ out,
    float* __restrict__ ntotp,
    int R)
{
    const int k = threadIdx.x;

    float n = 0.f;
    #pragma unroll 4
    for (int r = 0; r < R; ++r) n += cnt[(size_t)r * KB_NUM + k];

    float ncs = cluster_size[k] * DECAY_F + (1.0f - DECAY_F) * n;
    out[NCS_OFF + k] = ncs;

    __shared__ float red[KB_NUM];

    red[k] = ncs;
    __syncthreads();
    for (int s = KB_NUM / 2; s > 0; s >>= 1) {
        if (k < s) red[k] += red[k + s];
        __syncthreads();
    }
    if (k == 0) ntotp[0] = red[0];
    __syncthreads();

    float p = n * (1.0f / (float)NTOK);
    red[k] = p * logf(p + 1e-10f);
    __syncthreads();
    for (int s = KB_NUM / 2; s > 0; s >>= 1) {
        if (k < s) red[k] += red[k + s];
        __syncthreads();
    }
    if (k == 0) {
        out[PLEX_OFF] = expf(-red[0]);
        out[LOSS_OFF] = 0.25f * lossAcc[0] * (1.0f / (float)(BSZ * DIMC * TLEN));
    }
}

// ---------------------------------------------------------------------------
// Kernel 4: embedding update — 512 blocks x 64 threads
// ---------------------------------------------------------------------------
__global__ __launch_bounds__(64) void vq_embed_kernel(
    const float* __restrict__ embed_avg,
    const float* __restrict__ esum,
    const float* __restrict__ ntotp,
    float* __restrict__ out,
    int R)
{
    const int k = blockIdx.x;
    const int c = threadIdx.x;

    float es = 0.f;
    #pragma unroll 4
    for (int r = 0; r < R; ++r)
        es += esum[((size_t)r * KB_NUM + k) * DIMC + c];

    float nea = embed_avg[(size_t)k * DIMC + c] * DECAY_F + (1.0f - DECAY_F) * es;
    out[NEA_OFF + (size_t)k * DIMC + c] = nea;

    float ncs  = out[NCS_OFF + k];
    float ntot = ntotp[0];
    float denom = (ncs + EPS_F) / (ntot + (float)KB_NUM * EPS_F) * ntot;
    out[NEMB_OFF + (size_t)k * DIMC + c] = nea / denom;
}

// ---------------------------------------------------------------------------
extern "C" void kernel_launch(void* const* d_in, const int* in_sizes, int n_in,
                              void* d_out, int out_size, void* d_ws, size_t ws_size,
                              hipStream_t stream)
{
    const float* z            = (const float*)d_in[0];
    const float* emb          = (const float*)d_in[1];
    const float* cluster_size = (const float*)d_in[2];
    const float* embed_avg    = (const float*)d_in[3];
    float* out = (float*)d_out;

    char* ws = (char*)d_ws;
    float*     lossAcc = (float*)ws;                 // 1 f32
    float*     ntotp   = (float*)(ws + 64);          // 1 f32
    float*     enorm   = (float*)(ws + 256);         // 512 f32
    _Float16*  eh      = (_Float16*)(ws + 4096);     // 512*64 f16 = 64 KB
    _Float16*  el      = (_Float16*)(ws + 4096 + 65536);  // 64 KB
    const size_t CNT_OFF = 4096 + 131072;            // 135168
    const size_t perR = (size_t)(KB_NUM + KB_NUM * DIMC) * sizeof(float); // 133120

    int R = 1;
    if (ws_size > CNT_OFF + perR)
        R = (int)((ws_size - CNT_OFF) / perR);
    if (R < 1) R = 1;
    if (R > 16) R = 16;

    float* cnt  = (float*)(ws + CNT_OFF);    // [R][KB_NUM]
    float* esum = cnt + (size_t)R * KB_NUM;  // [R][KB_NUM*DIMC]

    // single memset covers lossAcc/ntotp + cnt + esum (eh/el rewritten by prep)
    hipMemsetAsync(ws, 0, CNT_OFF + (size_t)R * perR, stream);

    vq_prep_e<<<dim3(KB_NUM), dim3(DIMC), 0, stream>>>(emb, eh, el, enorm);

    vq_main_kernel<<<dim3(NTOK / MTOK), dim3(256), 0, stream>>>(
        z, emb, eh, el, enorm, out, lossAcc);

    vq_bin_kernel<<<dim3(NTOK / K2_SPAN), dim3(256), 0, stream>>>(z, out, cnt, esum, R);

    vq_stats_kernel<<<dim3(1), dim3(512), 0, stream>>>(
        cluster_size, cnt, lossAcc, out, ntotp, R);

    vq_embed_kernel<<<dim3(KB_NUM), dim3(DIMC), 0, stream>>>(
        embed_avg, esum, ntotp, out, R);
}

// Round 8
// 174.126 us; speedup vs baseline: 1.1453x; 1.1453x over previous
//
#include <hip/hip_runtime.h>
#include <math.h>

#define KB_NUM 512
#define DIMC 64
#define BSZ 32
#define TLEN 4096
#define NTOK (BSZ * TLEN)          // 131072
#define DECAY_F 0.99f
#define EPS_F 1e-5f

// output offsets (flat f32, reference return order)
#define Q_OFF    ((size_t)0)
#define IDX_OFF  ((size_t)BSZ * DIMC * TLEN)        // 8388608
#define LOSS_OFF (IDX_OFF + (size_t)NTOK)           // 8519680
#define PLEX_OFF (LOSS_OFF + 1)                     // 8519681
#define NEMB_OFF (PLEX_OFF + 1)                     // 8519682
#define NCS_OFF  (NEMB_OFF + (size_t)KB_NUM * DIMC) // 8552450
#define NEA_OFF  (NCS_OFF + (size_t)KB_NUM)         // 8552962

typedef _Float16 f16x8 __attribute__((ext_vector_type(8)));
typedef float    f32x4 __attribute__((ext_vector_type(4)));

// ---------------------------------------------------------------------------
// Kernel 0: prep embedding — f16 hi/lo split into FRAGMENT-MAJOR layout
// efrag[(kgrp*2+ks)*2 + hl][lane 0..63][8 f16]:
//   code = kgrp*16 + (lane&15), ch = ks*32 + (lane>>4)*8 + j
// -> main's A-load for (kgrp,ks,hl) is base + lane*8 f16: one contiguous
//    1KB wave-load (8 sequential lines) instead of 16 scattered lines.
// Also 0.5*||e||^2 (fp32), bit-identical to prior rounds.
// ---------------------------------------------------------------------------
__global__ __launch_bounds__(64) void vq_prep_e(
    const float* __restrict__ emb,
    _Float16* __restrict__ efrag,
    float* __restrict__ enorm)
{
    const int k = blockIdx.x;
    const int c = threadIdx.x;
    float v = emb[(size_t)k * DIMC + c];
    _Float16 h = (_Float16)v;
    _Float16 l = (_Float16)(v - (float)h);

    const int kgrp = k >> 4, row = k & 15;
    const int ks = c >> 5, seg = (c & 31) >> 3, j = c & 7;
    const int lane = seg * 16 + row;
    const size_t base = ((size_t)(kgrp * 2 + ks) * 2) * 512;
    efrag[base + (size_t)lane * 8 + j]       = h;   // hl = 0
    efrag[base + 512 + (size_t)lane * 8 + j] = l;   // hl = 1

    float s = v * v;
    #pragma unroll
    for (int off = 32; off > 0; off >>= 1)
        s += __shfl_down(s, off, 64);
    if (c == 0) enorm[k] = 0.5f * s;
}

// ---------------------------------------------------------------------------
// Kernel 1: MFMA argmin + quantize + loss  (round-6 structure, 82 µs base)
// block = 256 thr = 4 waves; tile = 256 tokens x 512 codes (full K).
// Wave w owns tokens [w*64, w*64+64): 4 token-tiles x 32 code-tiles,
// K=64 in 2 MFMA k-steps; 4-term f16 hi/lo MFMA = fp32-class precision.
// Only change vs round 6: A-operands read from efrag (coalesced 1KB loads);
// per-lane values bit-identical to round 6.
// ---------------------------------------------------------------------------
__global__ __launch_bounds__(256, 2) void vq_main_kernel(
    const float* __restrict__ z,
    const float* __restrict__ emb,
    const _Float16* __restrict__ efrag,
    const float* __restrict__ enorm,
    float* __restrict__ out,
    float* __restrict__ lossAcc)
{
    __shared__ float zs[256 * 65];   // [token][ch], pad 65 -> conflict-free

    const int tid = threadIdx.x;
    const int w   = tid >> 6;
    const int ln  = tid & 63;
    const int bk  = blockIdx.x;
    const int b   = bk >> 4;               // 16 blocks per batch row
    const int t0  = (bk & 15) << 8;        // 256 tokens per block

    const float* zg = z + (size_t)b * (DIMC * TLEN) + t0;

    // stage: transpose z[c][t] -> zs[t][c]; coalesced global, conflict-free LDS
    #pragma unroll 8
    for (int c = 0; c < DIMC; ++c)
        zs[tid * 65 + c] = zg[(size_t)c * TLEN + tid];
    __syncthreads();

    // build B fragments once (held in VGPRs for the whole K-loop)
    f16x8 zhf[4][2], zlf[4][2];
    #pragma unroll
    for (int tt = 0; tt < 4; ++tt) {
        #pragma unroll
        for (int ks = 0; ks < 2; ++ks) {
            const float* zrow = &zs[(w * 64 + tt * 16 + (ln & 15)) * 65
                                    + ks * 32 + ((ln >> 4) << 3)];
            #pragma unroll
            for (int j = 0; j < 8; ++j) {
                float v = zrow[j];
                _Float16 h = (_Float16)v;
                zhf[tt][ks][j] = h;
                zlf[tt][ks][j] = (_Float16)(v - (float)h);
            }
        }
    }

    float bv[4] = {3.4e38f, 3.4e38f, 3.4e38f, 3.4e38f};
    int   bi[4] = {0, 0, 0, 0};

    #pragma unroll 1
    for (int chunk = 0; chunk < 8; ++chunk) {        // 64 codes per chunk
        f32x4 acc[4][4];
        #pragma unroll
        for (int ct = 0; ct < 4; ++ct)
            #pragma unroll
            for (int tt = 0; tt < 4; ++tt)
                acc[ct][tt] = (f32x4){0.f, 0.f, 0.f, 0.f};

        #pragma unroll
        for (int ct = 0; ct < 4; ++ct) {
            const int kgrp = chunk * 4 + ct;
            // 4 consecutive 1KB wave-loads: [ks0:h][ks0:l][ks1:h][ks1:l]
            const _Float16* fb = efrag + ((size_t)kgrp * 4) * 512
                                       + (size_t)ln * 8;
            f16x8 ah[2], al[2];
            ah[0] = *(const f16x8*)(fb);
            al[0] = *(const f16x8*)(fb + 512);
            ah[1] = *(const f16x8*)(fb + 1024);
            al[1] = *(const f16x8*)(fb + 1536);

            #pragma unroll
            for (int ks = 0; ks < 2; ++ks) {
                #pragma unroll
                for (int tt = 0; tt < 4; ++tt)
                    acc[ct][tt] = __builtin_amdgcn_mfma_f32_16x16x32_f16(
                        ah[ks], zhf[tt][ks], acc[ct][tt], 0, 0, 0);
                #pragma unroll
                for (int tt = 0; tt < 4; ++tt)
                    acc[ct][tt] = __builtin_amdgcn_mfma_f32_16x16x32_f16(
                        ah[ks], zlf[tt][ks], acc[ct][tt], 0, 0, 0);
                #pragma unroll
                for (int tt = 0; tt < 4; ++tt)
                    acc[ct][tt] = __builtin_amdgcn_mfma_f32_16x16x32_f16(
                        al[ks], zhf[tt][ks], acc[ct][tt], 0, 0, 0);
                #pragma unroll
                for (int tt = 0; tt < 4; ++tt)
                    acc[ct][tt] = __builtin_amdgcn_mfma_f32_16x16x32_f16(
                        al[ks], zlf[tt][ks], acc[ct][tt], 0, 0, 0);
            }
        }

        // fold: s = 0.5||e||^2 - z.e ; ascending code order (chunk, ct, reg)
        #pragma unroll
        for (int ct = 0; ct < 4; ++ct) {
            const int cb = chunk * 64 + ct * 16 + ((ln >> 4) << 2);
            float4 en = *(const float4*)(enorm + cb);
            const float e0 = en.x, e1 = en.y, e2 = en.z, e3 = en.w;
            #pragma unroll
            for (int tt = 0; tt < 4; ++tt) {
                float s0 = e0 - acc[ct][tt][0];
                float s1 = e1 - acc[ct][tt][1];
                float s2 = e2 - acc[ct][tt][2];
                float s3 = e3 - acc[ct][tt][3];
                if (s0 < bv[tt]) { bv[tt] = s0; bi[tt] = cb; }
                if (s1 < bv[tt]) { bv[tt] = s1; bi[tt] = cb + 1; }
                if (s2 < bv[tt]) { bv[tt] = s2; bi[tt] = cb + 2; }
                if (s3 < bv[tt]) { bv[tt] = s3; bi[tt] = cb + 3; }
            }
        }
    }

    // cross-lane fold over the 4 row-groups (lane>>4); lower index wins ties
    #pragma unroll
    for (int mask = 16; mask <= 32; mask <<= 1) {
        #pragma unroll
        for (int tt = 0; tt < 4; ++tt) {
            float ov = __shfl_xor(bv[tt], mask, 64);
            int   oi = __shfl_xor(bi[tt], mask, 64);
            if (ov < bv[tt] || (ov == bv[tt] && oi < bi[tt])) {
                bv[tt] = ov; bi[tt] = oi;
            }
        }
    }

    // epilogue: lane ln owns token w*64 + ln
    const int g = ln >> 4;
    const int idxv = (g == 0) ? bi[0] : (g == 1) ? bi[1] : (g == 2) ? bi[2] : bi[3];
    const int tok = w * 64 + ln;

    out[IDX_OFF + (size_t)b * TLEN + t0 + tok] = (float)idxv;

    const float* er   = emb + (size_t)idxv * DIMC;   // fp32 codebook row
    const float* zrow = &zs[tok * 65];
    float* qo = out + (size_t)b * (DIMC * TLEN) + t0 + tok;

    float lsum = 0.f;
    #pragma unroll
    for (int c4 = 0; c4 < DIMC / 4; ++c4) {
        float4 ev = *(const float4*)(er + c4 * 4);
        float z0 = zrow[c4 * 4 + 0], z1 = zrow[c4 * 4 + 1];
        float z2 = zrow[c4 * 4 + 2], z3 = zrow[c4 * 4 + 3];
        float d0 = ev.x - z0, d1 = ev.y - z1, d2 = ev.z - z2, d3 = ev.w - z3;
        qo[(size_t)(c4 * 4 + 0) * TLEN] = z0 + d0;   // z + (q - z), ref rounding
        qo[(size_t)(c4 * 4 + 1) * TLEN] = z1 + d1;
        qo[(size_t)(c4 * 4 + 2) * TLEN] = z2 + d2;
        qo[(size_t)(c4 * 4 + 3) * TLEN] = z3 + d3;
        lsum = fmaf(d0, d0, lsum); lsum = fmaf(d1, d1, lsum);
        lsum = fmaf(d2, d2, lsum); lsum = fmaf(d3, d3, lsum);
    }

    #pragma unroll
    for (int off = 32; off > 0; off >>= 1)
        lsum += __shfl_down(lsum, off, 64);
    if (ln == 0) atomicAdd(lossAcc, lsum);
}

// ---------------------------------------------------------------------------
// Kernel 2: segment-sum binning via LDS accumulator, replica-atomic flush
// grid = 128 blocks x 256 thr; thread = 4 consecutive tokens (float4 over t)
// ---------------------------------------------------------------------------
__global__ __launch_bounds__(256, 1) void vq_bin_kernel(
    const float* __restrict__ z,
    const float* __restrict__ out,    // reads idx at IDX_OFF
    float* __restrict__ cnt,          // [R][KB_NUM]
    float* __restrict__ esum,         // [R][KB_NUM*DIMC]
    int R)
{
    __shared__ float acc[KB_NUM][DIMC + 1];
    __shared__ float scnt[KB_NUM];

    const int tid = threadIdx.x;
    for (int j = tid; j < KB_NUM * (DIMC + 1); j += 256) ((float*)acc)[j] = 0.f;
    for (int j = tid; j < KB_NUM; j += 256) scnt[j] = 0.f;
    __syncthreads();

    // 4 consecutive tokens per thread; block = 1024 tokens (same batch row)
    const int gt = blockIdx.x * 1024 + tid * 4;
    const int b  = gt >> 12;
    const int t  = gt & (TLEN - 1);

    float4 fi = *(const float4*)(out + IDX_OFF + gt);
    const int i0 = (int)fi.x, i1 = (int)fi.y, i2 = (int)fi.z, i3 = (int)fi.w;
    atomicAdd(&scnt[i0], 1.0f);
    atomicAdd(&scnt[i1], 1.0f);
    atomicAdd(&scnt[i2], 1.0f);
    atomicAdd(&scnt[i3], 1.0f);

    const float* zp = z + (size_t)b * (DIMC * TLEN) + t;
    #pragma unroll 4
    for (int c = 0; c < DIMC; ++c) {
        float4 zv = *(const float4*)(zp + (size_t)c * TLEN);  // 1KB/wave, coalesced
        atomicAdd(&acc[i0][c], zv.x);
        atomicAdd(&acc[i1][c], zv.y);
        atomicAdd(&acc[i2][c], zv.z);
        atomicAdd(&acc[i3][c], zv.w);
    }
    __syncthreads();

    const int r = (int)((unsigned)blockIdx.x % (unsigned)R);
    for (int j = tid; j < KB_NUM * DIMC; j += 256) {
        const int k = j >> 6, c = j & 63;
        float v = acc[k][c];
        if (v != 0.f) atomicAdd(esum + (size_t)r * (KB_NUM * DIMC) + j, v);
    }
    for (int j = tid; j < KB_NUM; j += 256) {
        float v = scnt[j];
        if (v != 0.f) atomicAdd(cnt + (size_t)r * KB_NUM + j, v);
    }
}

// ---------------------------------------------------------------------------
// Kernel 3: stats — new_cluster_size, n_tot, perplexity, loss
// ---------------------------------------------------------------------------
__global__ __launch_bounds__(512) void vq_stats_kernel(
    const float* __restrict__ cluster_size,
    const float* __restrict__ cnt,
    const float* __restrict__ lossAcc,
    float* __restrict__ out,
    float* __restrict__ ntotp,
    int R)
{
    const int k = threadIdx.x;

    float n = 0.f;
    #pragma unroll 4
    for (int r = 0; r < R; ++r) n += cnt[(size_t)r * KB_NUM + k];

    float ncs = cluster_size[k] * DECAY_F + (1.0f - DECAY_F) * n;
    out[NCS_OFF + k] = ncs;

    __shared__ float red[KB_NUM];

    red[k] = ncs;
    __syncthreads();
    for (int s = KB_NUM / 2; s > 0; s >>= 1) {
        if (k < s) red[k] += red[k + s];
        __syncthreads();
    }
    if (k == 0) ntotp[0] = red[0];
    __syncthreads();

    float p = n * (1.0f / (float)NTOK);
    red[k] = p * logf(p + 1e-10f);
    __syncthreads();
    for (int s = KB_NUM / 2; s > 0; s >>= 1) {
        if (k < s) red[k] += red[k + s];
        __syncthreads();
    }
    if (k == 0) {
        out[PLEX_OFF] = expf(-red[0]);
        out[LOSS_OFF] = 0.25f * lossAcc[0] * (1.0f / (float)(BSZ * DIMC * TLEN));
    }
}

// ---------------------------------------------------------------------------
// Kernel 4: embedding update — 512 blocks x 64 threads
// ---------------------------------------------------------------------------
__global__ __launch_bounds__(64) void vq_embed_kernel(
    const float* __restrict__ embed_avg,
    const float* __restrict__ esum,
    const float* __restrict__ ntotp,
    float* __restrict__ out,
    int R)
{
    const int k = blockIdx.x;
    const int c = threadIdx.x;

    float es = 0.f;
    #pragma unroll 4
    for (int r = 0; r < R; ++r)
        es += esum[((size_t)r * KB_NUM + k) * DIMC + c];

    float nea = embed_avg[(size_t)k * DIMC + c] * DECAY_F + (1.0f - DECAY_F) * es;
    out[NEA_OFF + (size_t)k * DIMC + c] = nea;

    float ncs  = out[NCS_OFF + k];
    float ntot = ntotp[0];
    float denom = (ncs + EPS_F) / (ntot + (float)KB_NUM * EPS_F) * ntot;
    out[NEMB_OFF + (size_t)k * DIMC + c] = nea / denom;
}

// ---------------------------------------------------------------------------
extern "C" void kernel_launch(void* const* d_in, const int* in_sizes, int n_in,
                              void* d_out, int out_size, void* d_ws, size_t ws_size,
                              hipStream_t stream)
{
    const float* z            = (const float*)d_in[0];
    const float* emb          = (const float*)d_in[1];
    const float* cluster_size = (const float*)d_in[2];
    const float* embed_avg    = (const float*)d_in[3];
    float* out = (float*)d_out;

    char* ws = (char*)d_ws;
    float*     lossAcc = (float*)ws;                 // 1 f32
    float*     ntotp   = (float*)(ws + 64);          // 1 f32
    float*     enorm   = (float*)(ws + 256);         // 512 f32
    _Float16*  efrag   = (_Float16*)(ws + 4096);     // 512*64*2 f16 = 128 KB
    const size_t CNT_OFF = 4096 + 131072;            // 135168
    const size_t perR = (size_t)(KB_NUM + KB_NUM * DIMC) * sizeof(float); // 133120

    int R = 1;
    if (ws_size > CNT_OFF + perR)
        R = (int)((ws_size - CNT_OFF) / perR);
    if (R < 1) R = 1;
    if (R > 16) R = 16;

    float* cnt  = (float*)(ws + CNT_OFF);    // [R][KB_NUM]
    float* esum = cnt + (size_t)R * KB_NUM;  // [R][KB_NUM*DIMC]

    // single memset covers lossAcc/ntotp + cnt + esum (efrag rewritten by prep)
    hipMemsetAsync(ws, 0, CNT_OFF + (size_t)R * perR, stream);

    vq_prep_e<<<dim3(KB_NUM), dim3(DIMC), 0, stream>>>(emb, efrag, enorm);

    vq_main_kernel<<<dim3(NTOK / 256), dim3(256), 0, stream>>>(
        z, emb, efrag, enorm, out, lossAcc);

    vq_bin_kernel<<<dim3(NTOK / 1024), dim3(256), 0, stream>>>(z, out, cnt, esum, R);

    vq_stats_kernel<<<dim3(1), dim3(512), 0, stream>>>(
        cluster_size, cnt, lossAcc, out, ntotp, R);

    vq_embed_kernel<<<dim3(KB_NUM), dim3(DIMC), 0, stream>>>(
        embed_avg, esum, ntotp, out, R);
}

// Round 9
// 134.217 us; speedup vs baseline: 1.4859x; 1.2973x over previous
//
#include <hip/hip_runtime.h>
#include <math.h>

#define KB_NUM 512
#define DIMC 64
#define BSZ 32
#define TLEN 4096
#define NTOK (BSZ * TLEN)          // 131072
#define DECAY_F 0.99f
#define EPS_F 1e-5f

// output offsets (flat f32, reference return order)
#define Q_OFF    ((size_t)0)
#define IDX_OFF  ((size_t)BSZ * DIMC * TLEN)        // 8388608
#define LOSS_OFF (IDX_OFF + (size_t)NTOK)           // 8519680
#define PLEX_OFF (LOSS_OFF + 1)                     // 8519681
#define NEMB_OFF (PLEX_OFF + 1)                     // 8519682
#define NCS_OFF  (NEMB_OFF + (size_t)KB_NUM * DIMC) // 8552450
#define NEA_OFF  (NCS_OFF + (size_t)KB_NUM)         // 8552962

typedef _Float16 f16x8 __attribute__((ext_vector_type(8)));
typedef float    f32x4 __attribute__((ext_vector_type(4)));

// ---------------------------------------------------------------------------
// Kernel 0: prep embedding — f16 hi/lo split into FRAGMENT-MAJOR layout
// efrag[(kgrp*2+ks)*2 + hl][lane 0..63][8 f16]:
//   code = kgrp*16 + (lane&15), ch = ks*32 + (lane>>4)*8 + j
// -> main's A-load for (kgrp,ks,hl) is base + lane*8 f16: one contiguous
//    1KB wave-load. Also 0.5*||e||^2 (fp32), bit-identical to prior rounds.
// ---------------------------------------------------------------------------
__global__ __launch_bounds__(64) void vq_prep_e(
    const float* __restrict__ emb,
    _Float16* __restrict__ efrag,
    float* __restrict__ enorm)
{
    const int k = blockIdx.x;
    const int c = threadIdx.x;
    float v = emb[(size_t)k * DIMC + c];
    _Float16 h = (_Float16)v;
    _Float16 l = (_Float16)(v - (float)h);

    const int kgrp = k >> 4, row = k & 15;
    const int ks = c >> 5, seg = (c & 31) >> 3, j = c & 7;
    const int lane = seg * 16 + row;
    const size_t base = ((size_t)(kgrp * 2 + ks) * 2) * 512;
    efrag[base + (size_t)lane * 8 + j]       = h;   // hl = 0
    efrag[base + 512 + (size_t)lane * 8 + j] = l;   // hl = 1

    float s = v * v;
    #pragma unroll
    for (int off = 32; off > 0; off >>= 1)
        s += __shfl_down(s, off, 64);
    if (c == 0) enorm[k] = 0.5f * s;
}

// ---------------------------------------------------------------------------
// Kernel 1: MFMA argmin + quantize + loss  (unchanged from round 8)
// block = 256 thr = 4 waves; tile = 256 tokens x 512 codes (full K).
// ---------------------------------------------------------------------------
__global__ __launch_bounds__(256, 2) void vq_main_kernel(
    const float* __restrict__ z,
    const float* __restrict__ emb,
    const _Float16* __restrict__ efrag,
    const float* __restrict__ enorm,
    float* __restrict__ out,
    float* __restrict__ lossAcc)
{
    __shared__ float zs[256 * 65];   // [token][ch], pad 65 -> conflict-free

    const int tid = threadIdx.x;
    const int w   = tid >> 6;
    const int ln  = tid & 63;
    const int bk  = blockIdx.x;
    const int b   = bk >> 4;               // 16 blocks per batch row
    const int t0  = (bk & 15) << 8;        // 256 tokens per block

    const float* zg = z + (size_t)b * (DIMC * TLEN) + t0;

    // stage: transpose z[c][t] -> zs[t][c]; coalesced global, conflict-free LDS
    #pragma unroll 8
    for (int c = 0; c < DIMC; ++c)
        zs[tid * 65 + c] = zg[(size_t)c * TLEN + tid];
    __syncthreads();

    // build B fragments once (held in VGPRs for the whole K-loop)
    f16x8 zhf[4][2], zlf[4][2];
    #pragma unroll
    for (int tt = 0; tt < 4; ++tt) {
        #pragma unroll
        for (int ks = 0; ks < 2; ++ks) {
            const float* zrow = &zs[(w * 64 + tt * 16 + (ln & 15)) * 65
                                    + ks * 32 + ((ln >> 4) << 3)];
            #pragma unroll
            for (int j = 0; j < 8; ++j) {
                float v = zrow[j];
                _Float16 h = (_Float16)v;
                zhf[tt][ks][j] = h;
                zlf[tt][ks][j] = (_Float16)(v - (float)h);
            }
        }
    }

    float bv[4] = {3.4e38f, 3.4e38f, 3.4e38f, 3.4e38f};
    int   bi[4] = {0, 0, 0, 0};

    #pragma unroll 1
    for (int chunk = 0; chunk < 8; ++chunk) {        // 64 codes per chunk
        f32x4 acc[4][4];
        #pragma unroll
        for (int ct = 0; ct < 4; ++ct)
            #pragma unroll
            for (int tt = 0; tt < 4; ++tt)
                acc[ct][tt] = (f32x4){0.f, 0.f, 0.f, 0.f};

        #pragma unroll
        for (int ct = 0; ct < 4; ++ct) {
            const int kgrp = chunk * 4 + ct;
            // 4 consecutive 1KB wave-loads: [ks0:h][ks0:l][ks1:h][ks1:l]
            const _Float16* fb = efrag + ((size_t)kgrp * 4) * 512
                                       + (size_t)ln * 8;
            f16x8 ah[2], al[2];
            ah[0] = *(const f16x8*)(fb);
            al[0] = *(const f16x8*)(fb + 512);
            ah[1] = *(const f16x8*)(fb + 1024);
            al[1] = *(const f16x8*)(fb + 1536);

            #pragma unroll
            for (int ks = 0; ks < 2; ++ks) {
                #pragma unroll
                for (int tt = 0; tt < 4; ++tt)
                    acc[ct][tt] = __builtin_amdgcn_mfma_f32_16x16x32_f16(
                        ah[ks], zhf[tt][ks], acc[ct][tt], 0, 0, 0);
                #pragma unroll
                for (int tt = 0; tt < 4; ++tt)
                    acc[ct][tt] = __builtin_amdgcn_mfma_f32_16x16x32_f16(
                        ah[ks], zlf[tt][ks], acc[ct][tt], 0, 0, 0);
                #pragma unroll
                for (int tt = 0; tt < 4; ++tt)
                    acc[ct][tt] = __builtin_amdgcn_mfma_f32_16x16x32_f16(
                        al[ks], zhf[tt][ks], acc[ct][tt], 0, 0, 0);
                #pragma unroll
                for (int tt = 0; tt < 4; ++tt)
                    acc[ct][tt] = __builtin_amdgcn_mfma_f32_16x16x32_f16(
                        al[ks], zlf[tt][ks], acc[ct][tt], 0, 0, 0);
            }
        }

        // fold: s = 0.5||e||^2 - z.e ; ascending code order (chunk, ct, reg)
        #pragma unroll
        for (int ct = 0; ct < 4; ++ct) {
            const int cb = chunk * 64 + ct * 16 + ((ln >> 4) << 2);
            float4 en = *(const float4*)(enorm + cb);
            const float e0 = en.x, e1 = en.y, e2 = en.z, e3 = en.w;
            #pragma unroll
            for (int tt = 0; tt < 4; ++tt) {
                float s0 = e0 - acc[ct][tt][0];
                float s1 = e1 - acc[ct][tt][1];
                float s2 = e2 - acc[ct][tt][2];
                float s3 = e3 - acc[ct][tt][3];
                if (s0 < bv[tt]) { bv[tt] = s0; bi[tt] = cb; }
                if (s1 < bv[tt]) { bv[tt] = s1; bi[tt] = cb + 1; }
                if (s2 < bv[tt]) { bv[tt] = s2; bi[tt] = cb + 2; }
                if (s3 < bv[tt]) { bv[tt] = s3; bi[tt] = cb + 3; }
            }
        }
    }

    // cross-lane fold over the 4 row-groups (lane>>4); lower index wins ties
    #pragma unroll
    for (int mask = 16; mask <= 32; mask <<= 1) {
        #pragma unroll
        for (int tt = 0; tt < 4; ++tt) {
            float ov = __shfl_xor(bv[tt], mask, 64);
            int   oi = __shfl_xor(bi[tt], mask, 64);
            if (ov < bv[tt] || (ov == bv[tt] && oi < bi[tt])) {
                bv[tt] = ov; bi[tt] = oi;
            }
        }
    }

    // epilogue: lane ln owns token w*64 + ln
    const int g = ln >> 4;
    const int idxv = (g == 0) ? bi[0] : (g == 1) ? bi[1] : (g == 2) ? bi[2] : bi[3];
    const int tok = w * 64 + ln;

    out[IDX_OFF + (size_t)b * TLEN + t0 + tok] = (float)idxv;

    const float* er   = emb + (size_t)idxv * DIMC;   // fp32 codebook row
    const float* zrow = &zs[tok * 65];
    float* qo = out + (size_t)b * (DIMC * TLEN) + t0 + tok;

    float lsum = 0.f;
    #pragma unroll
    for (int c4 = 0; c4 < DIMC / 4; ++c4) {
        float4 ev = *(const float4*)(er + c4 * 4);
        float z0 = zrow[c4 * 4 + 0], z1 = zrow[c4 * 4 + 1];
        float z2 = zrow[c4 * 4 + 2], z3 = zrow[c4 * 4 + 3];
        float d0 = ev.x - z0, d1 = ev.y - z1, d2 = ev.z - z2, d3 = ev.w - z3;
        qo[(size_t)(c4 * 4 + 0) * TLEN] = z0 + d0;   // z + (q - z), ref rounding
        qo[(size_t)(c4 * 4 + 1) * TLEN] = z1 + d1;
        qo[(size_t)(c4 * 4 + 2) * TLEN] = z2 + d2;
        qo[(size_t)(c4 * 4 + 3) * TLEN] = z3 + d3;
        lsum = fmaf(d0, d0, lsum); lsum = fmaf(d1, d1, lsum);
        lsum = fmaf(d2, d2, lsum); lsum = fmaf(d3, d3, lsum);
    }

    #pragma unroll
    for (int off = 32; off > 0; off >>= 1)
        lsum += __shfl_down(lsum, off, 64);
    if (ln == 0) atomicAdd(lossAcc, lsum);
}

// ---------------------------------------------------------------------------
// Kernel 2: segment-sum binning via LDS accumulator, replica-atomic flush
// grid = 256 blocks (1/CU) x 512 thr (8 waves = 2/SIMD); 1 token/thread.
// Scalar z loads coalesced over 512 consecutive t; unroll 16 keeps ~16
// loads in flight (LDS atomics are fire-and-forget, no dep chain).
// ---------------------------------------------------------------------------
__global__ __launch_bounds__(512, 1) void vq_bin_kernel(
    const float* __restrict__ z,
    const float* __restrict__ out,    // reads idx at IDX_OFF
    float* __restrict__ cnt,          // [R][KB_NUM]
    float* __restrict__ esum,         // [R][KB_NUM*DIMC]
    int R)
{
    __shared__ float acc[KB_NUM][DIMC + 1];   // 133 KB, bank = (idx+c)%32
    __shared__ float scnt[KB_NUM];

    const int tid = threadIdx.x;
    for (int j = tid; j < KB_NUM * (DIMC + 1); j += 512) ((float*)acc)[j] = 0.f;
    scnt[tid] = 0.f;
    __syncthreads();

    const int gt = blockIdx.x * 512 + tid;    // flat token id = b*TLEN + t
    const int b  = gt >> 12;                  // TLEN = 4096
    const int t  = gt & (TLEN - 1);
    const int idx = (int)out[IDX_OFF + gt];
    atomicAdd(&scnt[idx], 1.0f);

    const float* zp = z + (size_t)b * (DIMC * TLEN) + t;
    #pragma unroll 16
    for (int c = 0; c < DIMC; ++c) {
        float zv = zp[(size_t)c * TLEN];      // coalesced across 512 lanes
        atomicAdd(&acc[idx][c], zv);          // LDS ds_add, no return
    }
    __syncthreads();

    // flush to replica r (contiguous addresses per wave -> coalesced RMW)
    const int r = (int)((unsigned)blockIdx.x % (unsigned)R);
    for (int j = tid; j < KB_NUM * DIMC; j += 512) {
        const int k = j >> 6, c = j & 63;
        float v = acc[k][c];
        if (v != 0.f) atomicAdd(esum + (size_t)r * (KB_NUM * DIMC) + j, v);
    }
    {
        float v = scnt[tid];
        if (v != 0.f) atomicAdd(cnt + (size_t)r * KB_NUM + tid, v);
    }
}

// ---------------------------------------------------------------------------
// Kernel 3: stats — new_cluster_size, n_tot, perplexity, loss
// ---------------------------------------------------------------------------
__global__ __launch_bounds__(512) void vq_stats_kernel(
    const float* __restrict__ cluster_size,
    const float* __restrict__ cnt,
    const float* __restrict__ lossAcc,
    float* __restrict__ out,
    float* __restrict__ ntotp,
    int R)
{
    const int k = threadIdx.x;

    float n = 0.f;
    #pragma unroll 4
    for (int r = 0; r < R; ++r) n += cnt[(size_t)r * KB_NUM + k];

    float ncs = cluster_size[k] * DECAY_F + (1.0f - DECAY_F) * n;
    out[NCS_OFF + k] = ncs;

    __shared__ float red[KB_NUM];

    red[k] = ncs;
    __syncthreads();
    for (int s = KB_NUM / 2; s > 0; s >>= 1) {
        if (k < s) red[k] += red[k + s];
        __syncthreads();
    }
    if (k == 0) ntotp[0] = red[0];
    __syncthreads();

    float p = n * (1.0f / (float)NTOK);
    red[k] = p * logf(p + 1e-10f);
    __syncthreads();
    for (int s = KB_NUM / 2; s > 0; s >>= 1) {
        if (k < s) red[k] += red[k + s];
        __syncthreads();
    }
    if (k == 0) {
        out[PLEX_OFF] = expf(-red[0]);
        out[LOSS_OFF] = 0.25f * lossAcc[0] * (1.0f / (float)(BSZ * DIMC * TLEN));
    }
}

// ---------------------------------------------------------------------------
// Kernel 4: embedding update — 512 blocks x 64 threads
// ---------------------------------------------------------------------------
__global__ __launch_bounds__(64) void vq_embed_kernel(
    const float* __restrict__ embed_avg,
    const float* __restrict__ esum,
    const float* __restrict__ ntotp,
    float* __restrict__ out,
    int R)
{
    const int k = blockIdx.x;
    const int c = threadIdx.x;

    float es = 0.f;
    #pragma unroll 4
    for (int r = 0; r < R; ++r)
        es += esum[((size_t)r * KB_NUM + k) * DIMC + c];

    float nea = embed_avg[(size_t)k * DIMC + c] * DECAY_F + (1.0f - DECAY_F) * es;
    out[NEA_OFF + (size_t)k * DIMC + c] = nea;

    float ncs  = out[NCS_OFF + k];
    float ntot = ntotp[0];
    float denom = (ncs + EPS_F) / (ntot + (float)KB_NUM * EPS_F) * ntot;
    out[NEMB_OFF + (size_t)k * DIMC + c] = nea / denom;
}

// ---------------------------------------------------------------------------
extern "C" void kernel_launch(void* const* d_in, const int* in_sizes, int n_in,
                              void* d_out, int out_size, void* d_ws, size_t ws_size,
                              hipStream_t stream)
{
    const float* z            = (const float*)d_in[0];
    const float* emb          = (const float*)d_in[1];
    const float* cluster_size = (const float*)d_in[2];
    const float* embed_avg    = (const float*)d_in[3];
    float* out = (float*)d_out;

    char* ws = (char*)d_ws;
    float*     lossAcc = (float*)ws;                 // 1 f32
    float*     ntotp   = (float*)(ws + 64);          // 1 f32
    float*     enorm   = (float*)(ws + 256);         // 512 f32
    _Float16*  efrag   = (_Float16*)(ws + 4096);     // 512*64*2 f16 = 128 KB
    const size_t CNT_OFF = 4096 + 131072;            // 135168
    const size_t perR = (size_t)(KB_NUM + KB_NUM * DIMC) * sizeof(float); // 133120

    int R = 1;
    if (ws_size > CNT_OFF + perR)
        R = (int)((ws_size - CNT_OFF) / perR);
    if (R < 1) R = 1;
    if (R > 16) R = 16;

    float* cnt  = (float*)(ws + CNT_OFF);    // [R][KB_NUM]
    float* esum = cnt + (size_t)R * KB_NUM;  // [R][KB_NUM*DIMC]

    // single memset covers lossAcc/ntotp + cnt + esum (efrag rewritten by prep)
    hipMemsetAsync(ws, 0, CNT_OFF + (size_t)R * perR, stream);

    vq_prep_e<<<dim3(KB_NUM), dim3(DIMC), 0, stream>>>(emb, efrag, enorm);

    vq_main_kernel<<<dim3(NTOK / 256), dim3(256), 0, stream>>>(
        z, emb, efrag, enorm, out, lossAcc);

    vq_bin_kernel<<<dim3(NTOK / 512), dim3(512), 0, stream>>>(z, out, cnt, esum, R);

    vq_stats_kernel<<<dim3(1), dim3(512), 0, stream>>>(
        cluster_size, cnt, lossAcc, out, ntotp, R);

    vq_embed_kernel<<<dim3(KB_NUM), dim3(DIMC), 0, stream>>>(
        embed_avg, esum, ntotp, out, R);
}